// Round 10
// baseline (249.925 us; speedup 1.0000x reference)
//
#include <hip/hip_runtime.h>

#define VOCAB 53
#define EDIM  16
#define H     32
#define SEQ   512
#define BATCH 4096
#define LOG2E 1.4426950408889634f
#define XRS   132   // xg row stride in f32 words (%4==0 for b128 alignment)
#define HS    72    // h-buffer per-col stride in f16 (2-way banks, free)
#define RSC   2048.0f      // residual scale (2^11): lo parts stay f16-normal
#define RSCI  (1.0f/2048.0f)
#define CPB   8     // real batch columns per block

typedef _Float16 f16x8 __attribute__((ext_vector_type(8)));
typedef float f32x4 __attribute__((ext_vector_type(4)));

__device__ __forceinline__ float exp2_hw(float x) {
    float r; asm("v_exp_f32 %0, %1" : "=v"(r) : "v"(x)); return r;
}
// rcp(1 + 2^xs): sigmoid when xs = -log2e * z (scales pre-folded into tables)
__device__ __forceinline__ float sig_exp2(float xs) {
    return __builtin_amdgcn_rcpf(1.0f + exp2_hw(xs));
}

// permuted row rp = 16*m + 4*s + g  <->  original W row g*32 + (4m+s)
// (mfma chunk m gives lane (q,c) the 4 gates i,f,g,o of unit 4m+q in D[0..3])
__device__ __forceinline__ void decode_row(int rp, int& orig, float& scale) {
    int m = rp >> 4, rem = rp & 15, s = rem >> 2, g = rem & 3;
    orig = g * 32 + 4 * m + s;
    scale = (g == 2) ? (-2.0f * LOG2E) : (-LOG2E);   // g doubled: tanh(g)=2*sig(2g)-1
}

// 512 blocks x 256 threads (4 waves). Each block owns 8 batch elements (MFMA
// cols 8-15 are padding); each wave owns TWO 16-row MFMA chunks (2w, 2w+1).
// Two blocks co-reside per CU -> two independent recurrence chains hide the
// per-step latency. h exchanged via double-buffered padded LDS tile, one
// barrier per step. Weights AND h carried as f16 hi + x2048-f16 residual;
// 3 MFMAs per chunk reconstruct near-f32 precision.
__global__ __launch_bounds__(256, 2)
void lstm_seq_classifier(const int* __restrict__ x,
                         const float* __restrict__ emb,
                         const float* __restrict__ W_ih,
                         const float* __restrict__ W_hh,
                         const float* __restrict__ b_ih,
                         const float* __restrict__ b_hh,
                         const float* __restrict__ W_fc,
                         const float* __restrict__ b_fc,
                         float* __restrict__ out) {
    __shared__ float xg_perm[VOCAB * XRS];                  // 27,984 B (f32 exact)
    __shared__ _Float16 whi[128 * 32];                      // 8,192 B
    __shared__ _Float16 wlo[128 * 32];                      // 8,192 B (x2048 residual)
    __shared__ __align__(16) _Float16 hhi_buf[2][16][HS];   // 4,608 B
    __shared__ __align__(16) _Float16 hlo_buf[2][16][HS];   // 4,608 B
    __shared__ float red[16 * 33];                          // 2,112 B

    const int tid  = threadIdx.x;
    const int lane = tid & 63;
    const int w    = tid >> 6;      // wave 0..3; owns chunks 2w, 2w+1
    const int col  = lane & 15;     // MFMA column (batch elem if <CPB)
    const int q    = lane >> 4;

    // ---- vocab -> permuted, scaled gate-preactivation table (f32 exact) ----
    for (int idx = tid; idx < VOCAB * 128; idx += 256) {
        int v = idx >> 7, rp = idx & 127;
        int orig; float scale; decode_row(rp, orig, scale);
        float acc = b_ih[orig] + b_hh[orig];
        const float* ev = emb + v * EDIM;
        const float* wr = W_ih + orig * EDIM;
#pragma unroll
        for (int e = 0; e < EDIM; ++e) acc += ev[e] * wr[e];
        xg_perm[v * XRS + rp] = scale * acc;
    }
    // ---- permuted scaled W_hh as f16 hi + scaled f16 residual ----
    for (int idx = tid; idx < 128 * 32; idx += 256) {
        int rp = idx >> 5, k = idx & 31;
        int orig; float scale; decode_row(rp, orig, scale);
        float wv = scale * W_hh[orig * H + k];
        _Float16 hi = (_Float16)wv;
        whi[idx] = hi;
        wlo[idx] = (_Float16)((wv - (float)hi) * RSC);
    }
    for (int idx = tid; idx < 2 * 16 * HS; idx += 256) {
        (&hhi_buf[0][0][0])[idx] = (_Float16)0.f;
        (&hlo_buf[0][0][0])[idx] = (_Float16)0.f;
    }
    __syncthreads();

    const int c0 = 2 * w, c1 = 2 * w + 1;        // this wave's row chunks
    const f16x8 Ahi0 = *reinterpret_cast<const f16x8*>(&whi[(16 * c0 + col) * 32 + 8 * q]);
    const f16x8 Alo0 = *reinterpret_cast<const f16x8*>(&wlo[(16 * c0 + col) * 32 + 8 * q]);
    const f16x8 Ahi1 = *reinterpret_cast<const f16x8*>(&whi[(16 * c1 + col) * 32 + 8 * q]);
    const f16x8 Alo1 = *reinterpret_cast<const f16x8*>(&wlo[(16 * c1 + col) * 32 + 8 * q]);

    // token stream; cols >= CPB are padding -> clamp reads in-bounds
    int elem = blockIdx.x * CPB + col;
    if (elem > BATCH - 1) elem = BATCH - 1;
    const long xb = (long)elem * SEQ;
    int vb = x[xb];
    int vc = x[xb + 1];
    f32x4 xg_cur0 = *reinterpret_cast<const f32x4*>(&xg_perm[vb * XRS + 16 * c0 + 4 * q]);
    f32x4 xg_cur1 = *reinterpret_cast<const f32x4*>(&xg_perm[vb * XRS + 16 * c1 + 4 * q]);

    float cc0 = 0.0f, hh0 = 0.0f;   // unit 8w+q state (this col)
    float cc1 = 0.0f, hh1 = 0.0f;   // unit 8w+4+q state

    for (int s = 0; s < SEQ; ++s) {
        int vn = x[xb + ((s + 2) & (SEQ - 1))];                          // prefetch s+2
        f32x4 xg_nxt0 = *reinterpret_cast<const f32x4*>(
            &xg_perm[vc * XRS + 16 * c0 + 4 * q]);                       // prefetch s+1
        f32x4 xg_nxt1 = *reinterpret_cast<const f32x4*>(
            &xg_perm[vc * XRS + 16 * c1 + 4 * q]);
        const int rb = s & 1;
        f16x8 Bhi = *reinterpret_cast<const f16x8*>(&hhi_buf[rb][col][8 * q]);
        f16x8 Blo = *reinterpret_cast<const f16x8*>(&hlo_buf[rb][col][8 * q]);

        // chunk 0 (unit 8w+q)
        f32x4 D0  = __builtin_amdgcn_mfma_f32_16x16x32_f16(Ahi0, Bhi, xg_cur0, 0, 0, 0);
        f32x4 Dr0 = __builtin_amdgcn_mfma_f32_16x16x32_f16(Alo0, Bhi,
                        f32x4{0.f, 0.f, 0.f, 0.f}, 0, 0, 0);
        Dr0 = __builtin_amdgcn_mfma_f32_16x16x32_f16(Ahi0, Blo, Dr0, 0, 0, 0);
        // chunk 1 (unit 8w+4+q) — independent chain, overlaps chunk 0
        f32x4 D1  = __builtin_amdgcn_mfma_f32_16x16x32_f16(Ahi1, Bhi, xg_cur1, 0, 0, 0);
        f32x4 Dr1 = __builtin_amdgcn_mfma_f32_16x16x32_f16(Alo1, Bhi,
                        f32x4{0.f, 0.f, 0.f, 0.f}, 0, 0, 0);
        Dr1 = __builtin_amdgcn_mfma_f32_16x16x32_f16(Ahi1, Blo, Dr1, 0, 0, 0);

        {   // cell update, unit 8w+q
            float zi = __builtin_fmaf(RSCI, Dr0[0], D0[0]);
            float zf = __builtin_fmaf(RSCI, Dr0[1], D0[1]);
            float zg = __builtin_fmaf(RSCI, Dr0[2], D0[2]);
            float zo = __builtin_fmaf(RSCI, Dr0[3], D0[3]);
            float si = sig_exp2(zi), sf = sig_exp2(zf);
            float ug = sig_exp2(zg), so = sig_exp2(zo);
            float gt = __builtin_fmaf(2.0f, ug, -1.0f);
            cc0 = __builtin_fmaf(sf, cc0, si * gt);
            float tc = __builtin_fmaf(2.0f, sig_exp2(-2.0f * LOG2E * cc0), -1.0f);
            hh0 = so * tc;
        }
        {   // cell update, unit 8w+4+q
            float zi = __builtin_fmaf(RSCI, Dr1[0], D1[0]);
            float zf = __builtin_fmaf(RSCI, Dr1[1], D1[1]);
            float zg = __builtin_fmaf(RSCI, Dr1[2], D1[2]);
            float zo = __builtin_fmaf(RSCI, Dr1[3], D1[3]);
            float si = sig_exp2(zi), sf = sig_exp2(zf);
            float ug = sig_exp2(zg), so = sig_exp2(zo);
            float gt = __builtin_fmaf(2.0f, ug, -1.0f);
            cc1 = __builtin_fmaf(sf, cc1, si * gt);
            float tc = __builtin_fmaf(2.0f, sig_exp2(-2.0f * LOG2E * cc1), -1.0f);
            hh1 = so * tc;
        }

        const int nb = (s + 1) & 1;
        _Float16 h0h = (_Float16)hh0, h1h = (_Float16)hh1;
        hhi_buf[nb][col][8 * w + q]     = h0h;
        hhi_buf[nb][col][8 * w + 4 + q] = h1h;
        hlo_buf[nb][col][8 * w + q]     = (_Float16)((hh0 - (float)h0h) * RSC);
        hlo_buf[nb][col][8 * w + 4 + q] = (_Float16)((hh1 - (float)h1h) * RSC);
        __syncthreads();
        xg_cur0 = xg_nxt0; xg_cur1 = xg_nxt1;
        vc = vn;
    }

    // ---- final FC (1 unit) + sigmoid over 32 units, cols 0..7 ----
    red[col * 33 + 8 * w + q]     = hh0 * W_fc[8 * w + q];
    red[col * 33 + 8 * w + 4 + q] = hh1 * W_fc[8 * w + 4 + q];
    __syncthreads();
    if (w == 0) {
        const float* rr = &red[col * 33];
        float p = 0.f;
#pragma unroll
        for (int u = 0; u < 8; ++u) p += rr[8 * q + u];
        p += __shfl_xor(p, 16);
        p += __shfl_xor(p, 32);
        if (lane < CPB) {
            out[blockIdx.x * CPB + lane] = sig_exp2(-LOG2E * (p + b_fc[0]));
        }
    }
}

extern "C" void kernel_launch(void* const* d_in, const int* in_sizes, int n_in,
                              void* d_out, int out_size, void* d_ws, size_t ws_size,
                              hipStream_t stream) {
    const int*   x    = (const int*)d_in[0];
    const float* emb  = (const float*)d_in[1];
    const float* W_ih = (const float*)d_in[2];
    const float* W_hh = (const float*)d_in[3];
    const float* b_ih = (const float*)d_in[4];
    const float* b_hh = (const float*)d_in[5];
    const float* W_fc = (const float*)d_in[6];
    const float* b_fc = (const float*)d_in[7];
    float* out = (float*)d_out;

    dim3 grid(BATCH / CPB);  // 512 blocks -> 2 per CU: two independent chains
    dim3 block(256);         // 4 waves, two mfma row-chunks each
    lstm_seq_classifier<<<grid, block, 0, stream>>>(x, emb, W_ih, W_hh,
                                                    b_ih, b_hh, W_fc, b_fc, out);
}

// Round 11
// 226.476 us; speedup vs baseline: 1.1035x; 1.1035x over previous
//
#include <hip/hip_runtime.h>

#define VOCAB 53
#define EDIM  16
#define H     32
#define SEQ   512
#define BATCH 4096
#define LOG2E 1.4426950408889634f
#define XRS   132   // xg row stride in f32 words (%4==0 for b128 alignment)
#define HUS   36    // h-buffer per-col stride in u32 (2-way banks, free)
#define RSC   2048.0f      // residual scale (2^11): lo parts stay f16-normal
#define RSCI  (1.0f/2048.0f)

typedef _Float16 f16x8 __attribute__((ext_vector_type(8)));
typedef float f32x4 __attribute__((ext_vector_type(4)));

__device__ __forceinline__ float exp2_hw(float x) {
    float r; asm("v_exp_f32 %0, %1" : "=v"(r) : "v"(x)); return r;
}
// rcp(1 + 2^xs): sigmoid when xs = -log2e * z (scales pre-folded into tables)
__device__ __forceinline__ float sig_exp2(float xs) {
    return __builtin_amdgcn_rcpf(1.0f + exp2_hw(xs));
}

// permuted row rp = 16*m + 4*s + g  <->  original W row g*32 + (4m+s)
// (mfma chunk m gives lane (q,c) the 4 gates i,f,g,o of unit 4m+q in D[0..3])
__device__ __forceinline__ void decode_row(int rp, int& orig, float& scale) {
    int m = rp >> 4, rem = rp & 15, s = rem >> 2, g = rem & 3;
    orig = g * 32 + 4 * m + s;
    scale = (g == 2) ? (-2.0f * LOG2E) : (-LOG2E);   // g doubled: tanh(g)=2*sig(2g)-1
}

// 256 blocks x 512 threads (8 waves). Each block owns 16 batch elements; each
// wave owns one 16-row MFMA chunk. h exchanged via a double-buffered LDS
// buffer of packed u32 = (hhi f16 | hlo f16) per unit: ONE ds_write_b32 per
// lane-step, two ds_read_b128 + bitop extraction per wave-step. Weights f16
// hi + x2048-f16 residual; 3 INDEPENDENT MFMAs reconstruct near-f32 precision.
// c is kept scaled by -2log2e so tanh(c) needs no extra multiply.
__global__ __launch_bounds__(512, 1)
void lstm_seq_classifier(const int* __restrict__ x,
                         const float* __restrict__ emb,
                         const float* __restrict__ W_ih,
                         const float* __restrict__ W_hh,
                         const float* __restrict__ b_ih,
                         const float* __restrict__ b_hh,
                         const float* __restrict__ W_fc,
                         const float* __restrict__ b_fc,
                         float* __restrict__ out) {
    __shared__ float xg_perm[VOCAB * XRS];                  // 27,984 B (f32 exact)
    __shared__ _Float16 whi[128 * 32];                      // 8,192 B
    __shared__ _Float16 wlo[128 * 32];                      // 8,192 B (x2048 residual)
    __shared__ __align__(16) unsigned hb[2][16][HUS];       // 4,608 B packed (hi|lo)
    __shared__ float red[16 * 33];                          // 2,112 B

    const int tid  = threadIdx.x;
    const int lane = tid & 63;
    const int w    = tid >> 6;      // wave index = mfma row-chunk m
    const int col  = lane & 15;     // batch column
    const int q    = lane >> 4;

    // ---- vocab -> permuted, scaled gate-preactivation table (f32 exact) ----
    for (int idx = tid; idx < VOCAB * 128; idx += 512) {
        int v = idx >> 7, rp = idx & 127;
        int orig; float scale; decode_row(rp, orig, scale);
        float acc = b_ih[orig] + b_hh[orig];
        const float* ev = emb + v * EDIM;
        const float* wr = W_ih + orig * EDIM;
#pragma unroll
        for (int e = 0; e < EDIM; ++e) acc += ev[e] * wr[e];
        xg_perm[v * XRS + rp] = scale * acc;
    }
    // ---- permuted scaled W_hh as f16 hi + scaled f16 residual ----
    for (int idx = tid; idx < 128 * 32; idx += 512) {
        int rp = idx >> 5, k = idx & 31;
        int orig; float scale; decode_row(rp, orig, scale);
        float wv = scale * W_hh[orig * H + k];
        _Float16 hi = (_Float16)wv;
        whi[idx] = hi;
        wlo[idx] = (_Float16)((wv - (float)hi) * RSC);
    }
    for (int idx = tid; idx < 2 * 16 * HUS; idx += 512)
        (&hb[0][0][0])[idx] = 0u;   // h = 0, residual = 0
    __syncthreads();

    // A fragments: chunk-row = col, k-slot j = unit 8q+j (identity k-order)
    const f16x8 Ahi = *reinterpret_cast<const f16x8*>(&whi[(16 * w + col) * 32 + 8 * q]);
    const f16x8 Alo = *reinterpret_cast<const f16x8*>(&wlo[(16 * w + col) * 32 + 8 * q]);

    const long xb = (long)(blockIdx.x * 16 + col) * SEQ;
    int vc = x[xb + 1];
    f32x4 xg_cur = *reinterpret_cast<const f32x4*>(&xg_perm[x[xb] * XRS + 16 * w + 4 * q]);

    // double-buffer pointers (swap each step)
    const unsigned* rd  = &hb[0][col][8 * q];   // read frag base, buf 0
    const unsigned* rdN = &hb[1][col][8 * q];
    unsigned* wr_  = &hb[1][col][4 * w + q];    // write slot, buf 1
    unsigned* wrN  = &hb[0][col][4 * w + q];

    float ccs = 0.0f, h = 0.0f;   // ccs = -2log2e * c

    const f32x4 zeroC = {0.f, 0.f, 0.f, 0.f};

    for (int s = 0; s < SEQ; ++s) {
        int vn = x[xb + ((s + 2) & (SEQ - 1))];                          // prefetch s+2
        f32x4 xg_nxt = *reinterpret_cast<const f32x4*>(
            &xg_perm[vc * XRS + 16 * w + 4 * q]);                        // prefetch s+1

        uint4 u0 = *reinterpret_cast<const uint4*>(rd);      // units 8q..8q+3
        uint4 u1 = *reinterpret_cast<const uint4*>(rd + 4);  // units 8q+4..8q+7
        union { unsigned u[4]; f16x8 v; } bh, bl;
        bh.u[0] = (u0.x & 0xFFFFu) | (u0.y << 16);
        bh.u[1] = (u0.z & 0xFFFFu) | (u0.w << 16);
        bh.u[2] = (u1.x & 0xFFFFu) | (u1.y << 16);
        bh.u[3] = (u1.z & 0xFFFFu) | (u1.w << 16);
        bl.u[0] = (u0.x >> 16) | (u0.y & 0xFFFF0000u);
        bl.u[1] = (u0.z >> 16) | (u0.w & 0xFFFF0000u);
        bl.u[2] = (u1.x >> 16) | (u1.y & 0xFFFF0000u);
        bl.u[3] = (u1.z >> 16) | (u1.w & 0xFFFF0000u);

        // three INDEPENDENT MFMAs (1-deep chain), then combine
        f32x4 D   = __builtin_amdgcn_mfma_f32_16x16x32_f16(Ahi, bh.v, xg_cur, 0, 0, 0);
        f32x4 Dra = __builtin_amdgcn_mfma_f32_16x16x32_f16(Alo, bh.v, zeroC, 0, 0, 0);
        f32x4 Drb = __builtin_amdgcn_mfma_f32_16x16x32_f16(Ahi, bl.v, zeroC, 0, 0, 0);

        float zi = __builtin_fmaf(RSCI, Dra[0] + Drb[0], D[0]);
        float zf = __builtin_fmaf(RSCI, Dra[1] + Drb[1], D[1]);
        float zg = __builtin_fmaf(RSCI, Dra[2] + Drb[2], D[2]);
        float zo = __builtin_fmaf(RSCI, Dra[3] + Drb[3], D[3]);

        float si = sig_exp2(zi);                         // sigma(i)
        float sf = sig_exp2(zf);                         // sigma(f)
        float ug = sig_exp2(zg);                         // sigma(2g)
        float so = sig_exp2(zo);                         // sigma(o)
        float t1 = __builtin_fmaf(-4.0f * LOG2E, ug, 2.0f * LOG2E);  // -2l2e*tanh(g)
        ccs = __builtin_fmaf(sf, ccs, si * t1);          // scaled cell
        float tc = __builtin_fmaf(2.0f, sig_exp2(ccs), -1.0f);       // tanh(c)
        h = so * tc;

        _Float16 hf = (_Float16)h;
        float lof = (h - (float)hf) * RSC;
        _Float16 lf = (_Float16)lof;
        unsigned pw = (unsigned)__builtin_bit_cast(unsigned short, hf)
                    | ((unsigned)__builtin_bit_cast(unsigned short, lf) << 16);
        wr_[0] = pw;
        __syncthreads();

        { const unsigned* t = rd; rd = rdN; rdN = t; }
        { unsigned* t = wr_; wr_ = wrN; wrN = t; }
        xg_cur = xg_nxt;
        vc = vn;
    }

    // ---- final FC (1 unit) + sigmoid: cross-wave reduce over the 32 units ----
    red[col * 33 + 4 * w + q] = h * W_fc[4 * w + q];
    __syncthreads();
    if (w == 0) {
        const float* rr = &red[col * 33];
        float p = 0.f;
#pragma unroll
        for (int u = 0; u < 8; ++u) p += rr[8 * q + u];
        p += __shfl_xor(p, 16);
        p += __shfl_xor(p, 32);
        if (lane < 16) {
            out[blockIdx.x * 16 + col] = sig_exp2(-LOG2E * (p + b_fc[0]));
        }
    }
}

extern "C" void kernel_launch(void* const* d_in, const int* in_sizes, int n_in,
                              void* d_out, int out_size, void* d_ws, size_t ws_size,
                              hipStream_t stream) {
    const int*   x    = (const int*)d_in[0];
    const float* emb  = (const float*)d_in[1];
    const float* W_ih = (const float*)d_in[2];
    const float* W_hh = (const float*)d_in[3];
    const float* b_ih = (const float*)d_in[4];
    const float* b_hh = (const float*)d_in[5];
    const float* W_fc = (const float*)d_in[6];
    const float* b_fc = (const float*)d_in[7];
    float* out = (float*)d_out;

    dim3 grid(BATCH / 16);   // 256 blocks: one 16-elem group per block
    dim3 block(512);         // 8 waves, one mfma row-chunk each
    lstm_seq_classifier<<<grid, block, 0, stream>>>(x, emb, W_ih, W_hh,
                                                    b_ih, b_hh, W_fc, b_fc, out);
}